// Round 22
// baseline (331.397 us; speedup 1.0000x reference)
//
#include <hip/hip_runtime.h>
#include <hip/hip_bf16.h>
#include <math.h>

typedef __bf16 bf16;
typedef __bf16 bf16x4 __attribute__((ext_vector_type(4)));
typedef __bf16 bf16x8 __attribute__((ext_vector_type(8)));
typedef float f32x4 __attribute__((ext_vector_type(4)));
typedef unsigned int u32x4 __attribute__((ext_vector_type(4)));

#define NHEADS 6
#define CDIM 192
#define IMG 56
#define NTOK 49
#define SHIFTV 3
#define XSTR 200   // padded row stride (bf16) for BufA/BufB: 400 B
#define VSTR 72    // padded stride for VT: 144 B
#define LOG2E 1.4426950408889634f
#define SCALE 0.17677669529663687f
#define MSKNEG (-100.0f * LOG2E)

#define MFMA(a, b, c) __builtin_amdgcn_mfma_f32_16x16x32_bf16(a, b, c, 0, 0, 0)

static __device__ __forceinline__ unsigned pack2bf(float lo, float hi) {
    unsigned short a = __builtin_bit_cast(unsigned short, (bf16)lo);
    unsigned short b = __builtin_bit_cast(unsigned short, (bf16)hi);
    return (unsigned)a | ((unsigned)b << 16);
}

// ---- weight prep: fp32 -> bf16, transposed to [N][K] ----
__global__ void prep_weights(const float* __restrict__ w_qkv, const float* __restrict__ w_proj,
                             bf16* __restrict__ wqkvT, bf16* __restrict__ wprojT) {
    int i = blockIdx.x * 256 + threadIdx.x;
    if (i < 576 * 192) {
        int n = i / 192, k = i % 192;
        wqkvT[i] = (bf16)w_qkv[k * 576 + n];
    }
    if (i < 192 * 192) {
        int n = i / 192, k = i % 192;
        wprojT[i] = (bf16)w_proj[k * 192 + n];
    }
}

__global__ __launch_bounds__(512, 4) void swin_block(
    const float* __restrict__ x, const float* __restrict__ gamma, const float* __restrict__ beta,
    const bf16* __restrict__ wqkvT, const float* __restrict__ b_qkv,
    const float* __restrict__ rel_table, const bf16* __restrict__ wprojT,
    const float* __restrict__ b_proj, float* __restrict__ out)
{
    __shared__ __align__(16) bf16 BufA[64 * XSTR];     // X (ph0-1), then K (in place)
    __shared__ __align__(16) bf16 BufB[64 * XSTR];     // Q (ph1-2), then O in place (ph2-3)
    __shared__ __align__(16) bf16 VTs[CDIM * VSTR];    // V transposed: [channel][token]
    __shared__ bf16 biasS[169 * NHEADS];               // rel-pos bias * log2e
    // total 80876 B -> 2 blocks/CU

    const int blk  = blockIdx.x;
    const int bimg = blk >> 6;
    const int wy   = (blk >> 3) & 7;
    const int wx   = blk & 7;
    const int tid  = threadIdx.x;
    const int wave = tid >> 6;   // 0..7
    const int lane = tid & 63;
    const int lr   = lane & 15;
    const int lq   = lane >> 4;
    const int h0   = wave & 1;
    const int cg   = wave >> 1;  // 0..3

    for (int i = tid; i < 169 * NHEADS; i += 512) biasS[i] = (bf16)(rel_table[i] * LOG2E);

    const bf16* wbase = wqkvT + (size_t)lr * CDIM + lq * 8;
#define WPTR(nt) (wbase + (size_t)(nt) * (16 * CDIM))
#define LOADW6(dst, p) do { const bf16* _p = (p); \
    _Pragma("unroll") for (int k = 0; k < 6; ++k) dst[k] = *(const bf16x8*)(_p + k * 32); } while (0)

    { // ---- phases 0-1 scope: bA/bB live only here ----
    bf16x8 bA[6], bB[6];

    // ---- phase 0: LN, 16 lanes per row (4 rows/wave/iter, 12 ch/lane); hoisted gamma/beta ----
    {
        const int c0 = lr * 12;
        const f32x4 gm0 = *(const f32x4*)&gamma[c0], gm1 = *(const f32x4*)&gamma[c0 + 4], gm2 = *(const f32x4*)&gamma[c0 + 8];
        const f32x4 bt0 = *(const f32x4*)&beta[c0],  bt1 = *(const f32x4*)&beta[c0 + 4],  bt2 = *(const f32x4*)&beta[c0 + 8];
        #pragma unroll
        for (int it = 0; it < 2; ++it) {
            const int t = it * 32 + wave * 4 + lq;   // 0..63, each (it,wave,lq) one row
            if (t < NTOK) {
                int ty = t / 7, tx = t % 7;
                int oy = wy * 7 + ty + SHIFTV; if (oy >= IMG) oy -= IMG;
                int ox = wx * 7 + tx + SHIFTV; if (ox >= IMG) ox -= IMG;
                const float* xp = x + (((size_t)bimg * IMG + oy) * IMG + ox) * CDIM + c0;
                f32x4 v0 = *(const f32x4*)(xp), v1 = *(const f32x4*)(xp + 4), v2 = *(const f32x4*)(xp + 8);
                float s = 0.f, ss = 0.f;
                #pragma unroll
                for (int r = 0; r < 4; ++r) {
                    s  += v0[r] + v1[r] + v2[r];
                    ss += v0[r] * v0[r] + v1[r] * v1[r] + v2[r] * v2[r];
                }
                #pragma unroll
                for (int off = 1; off < 16; off <<= 1) { s += __shfl_xor(s, off); ss += __shfl_xor(ss, off); }
                float mu  = s * (1.f / 192.f);
                float var = ss * (1.f / 192.f) - mu * mu;
                float rs  = rsqrtf(var + 1e-5f);
                bf16x4 o0, o1, o2;
                #pragma unroll
                for (int r = 0; r < 4; ++r) {
                    o0[r] = (bf16)((v0[r] - mu) * rs * gm0[r] + bt0[r]);
                    o1[r] = (bf16)((v1[r] - mu) * rs * gm1[r] + bt1[r]);
                    o2[r] = (bf16)((v2[r] - mu) * rs * gm2[r] + bt2[r]);
                }
                *(bf16x4*)&BufA[t * XSTR + c0    ] = o0;
                *(bf16x4*)&BufA[t * XSTR + c0 + 4] = o1;
                *(bf16x4*)&BufA[t * XSTR + c0 + 8] = o2;
            } else {
                bf16x4 z = {(bf16)0.f, (bf16)0.f, (bf16)0.f, (bf16)0.f};
                *(bf16x4*)&BufA[t * XSTR + c0    ] = z;
                *(bf16x4*)&BufA[t * XSTR + c0 + 4] = z;
                *(bf16x4*)&BufA[t * XSTR + c0 + 8] = z;
            }
        }
    }
    // prefetch first phase-1 weight hexad: ~300cy L2 latency hides under barrier + afrag ds_reads
    LOADW6(bA, WPTR(cg));
    __syncthreads();

    // ---- phase 1: QKV, software-pipelined weight loads (dual register buffers) ----
    {
        bf16x8 afrag[2][6];
        #pragma unroll
        for (int mm = 0; mm < 2; ++mm)
            #pragma unroll
            for (int k = 0; k < 6; ++k)
                afrag[mm][k] = *(const bf16x8*)&BufA[(32 * h0 + 16 * mm + lr) * XSTR + k * 32 + lq * 8];
        __syncthreads();   // all waves cached X before K overwrites BufA

        // Q/K (swapped): D token = 32h0+16mm+lr, channel packed (nt%12)*16+4lq+r
#define COMP_QK(buf, nt, dstb) do { \
    f32x4 a0 = {0.f,0.f,0.f,0.f}, a1 = {0.f,0.f,0.f,0.f}; \
    _Pragma("unroll") for (int k = 0; k < 6; ++k) { \
        a0 = MFMA(buf[k], afrag[0][k], a0); \
        a1 = MFMA(buf[k], afrag[1][k], a1); } \
    const int ccl_ = ((nt) % 12) * 16 + 4 * lq; \
    const f32x4 bq_ = *(const f32x4*)&b_qkv[(nt) * 16 + 4 * lq]; \
    bf16x4 v0_, v1_; \
    _Pragma("unroll") for (int r = 0; r < 4; ++r) { v0_[r] = (bf16)(a0[r] + bq_[r]); v1_[r] = (bf16)(a1[r] + bq_[r]); } \
    *(bf16x4*)&dstb[(32 * h0 + lr) * XSTR + ccl_] = v0_; \
    *(bf16x4*)&dstb[(32 * h0 + 16 + lr) * XSTR + ccl_] = v1_; } while (0)
        // V (unswapped): D channel = (nt-24)*16+lr, token packed 32h0+16mm+4lq+r
#define COMP_V(buf, nt) do { \
    f32x4 a0 = {0.f,0.f,0.f,0.f}, a1 = {0.f,0.f,0.f,0.f}; \
    _Pragma("unroll") for (int k = 0; k < 6; ++k) { \
        a0 = MFMA(afrag[0][k], buf[k], a0); \
        a1 = MFMA(afrag[1][k], buf[k], a1); } \
    const int cc_ = ((nt) - 24) * 16 + lr; \
    const float bb_ = b_qkv[384 + cc_]; \
    bf16x4 v0_, v1_; \
    _Pragma("unroll") for (int r = 0; r < 4; ++r) { v0_[r] = (bf16)(a0[r] + bb_); v1_[r] = (bf16)(a1[r] + bb_); } \
    *(bf16x4*)&VTs[cc_ * VSTR + 32 * h0 + 4 * lq] = v0_; \
    *(bf16x4*)&VTs[cc_ * VSTR + 32 * h0 + 16 + 4 * lq] = v1_; } while (0)

        LOADW6(bB, WPTR(cg + 4));  COMP_QK(bA, cg,      BufB);
        LOADW6(bA, WPTR(cg + 8));  COMP_QK(bB, cg + 4,  BufB);
        LOADW6(bB, WPTR(cg + 12)); COMP_QK(bA, cg + 8,  BufB);
        LOADW6(bA, WPTR(cg + 16)); COMP_QK(bB, cg + 12, BufA);
        LOADW6(bB, WPTR(cg + 20)); COMP_QK(bA, cg + 16, BufA);
        LOADW6(bA, WPTR(cg + 24)); COMP_QK(bB, cg + 20, BufA);
        LOADW6(bB, WPTR(cg + 28)); COMP_V (bA, cg + 24);
        LOADW6(bA, WPTR(cg + 32)); COMP_V (bB, cg + 28);
                                   COMP_V (bA, cg + 32);
    }
    } // ---- end phases 0-1 scope (bA/bB die) ----
    __syncthreads();

    // ---- phase 2: attention, swapped QK^T (S^T), LDS bias, NO-MAX softmax,
    //      DEFERRED normalization, permlane/swizzle P^T, setprio, Q-prefetch ----
    {
        const int m  = wave & 3;
        const int hg = wave >> 2;
        const int i  = 16 * m + lr;
        const int ic = i < NTOK ? i : NTOK - 1;
        const int iy = ic / 7, ix = ic % 7;
        const int ay = wy * 7 + iy, ax = wx * 7 + ix;
        const int ryi = (ay < 49) ? 0 : ((ay < 53) ? 1 : 2);
        const int rxi = (ax < 49) ? 0 : ((ax < 53) ? 1 : 2);
        int   rp[4][4];
        float msk[4][4];
        #pragma unroll
        for (int n = 0; n < 4; ++n)
            #pragma unroll
            for (int r = 0; r < 4; ++r) {
                int j = 16 * n + 4 * lq + r;
                if (j < NTOK) {
                    int jy = j / 7, jx = j % 7;
                    rp[n][r] = ((iy - jy + 6) * 13 + (ix - jx + 6)) * NHEADS;
                    int by = wy * 7 + jy, bx = wx * 7 + jx;
                    int ryj = (by < 49) ? 0 : ((by < 53) ? 1 : 2);
                    int rxj = (bx < 49) ? 0 : ((bx < 53) ? 1 : 2);
                    msk[n][r] = (ryi == ryj && rxi == rxj) ? 0.f : MSKNEG;
                } else { rp[n][r] = 0; msk[n][r] = -1e30f; }
            }
        const bool hi16 = (lane & 16) != 0;
        const float SC = SCALE * LOG2E;

        bf16x8 bq = *(const bf16x8*)&BufB[(16 * m + lr) * XSTR + (hg * 3) * 32 + lq * 8];

        #pragma unroll
        for (int hh = 0; hh < 3; ++hh) {
            const int h = hg * 3 + hh;
            f32x4 st[4];
            __builtin_amdgcn_s_setprio(1);
            #pragma unroll
            for (int n = 0; n < 4; ++n) {
                bf16x8 ak = *(const bf16x8*)&BufA[(16 * n + lr) * XSTR + h * 32 + lq * 8];
                st[n] = MFMA(ak, bq, (f32x4{0.f, 0.f, 0.f, 0.f}));
            }
            __builtin_amdgcn_s_setprio(0);
            float sum = 0.f;
            #pragma unroll
            for (int n = 0; n < 4; ++n)
                #pragma unroll
                for (int r = 0; r < 4; ++r) {
                    float e = exp2f(fmaf(st[n][r], SC, msk[n][r]) + (float)biasS[rp[n][r] + h]);
                    st[n][r] = e; sum += e;
                }
            if (hh < 2)
                bq = *(const bf16x8*)&BufB[(16 * m + lr) * XSTR + (h + 1) * 32 + lq * 8];
            unsigned pa0 = pack2bf(st[0][0], st[0][1]);
            unsigned pa1 = pack2bf(st[0][2], st[0][3]);
            unsigned pb0 = pack2bf(st[1][0], st[1][1]);
            unsigned pb1 = pack2bf(st[1][2], st[1][3]);
            unsigned pc0 = pack2bf(st[2][0], st[2][1]);
            unsigned pc1 = pack2bf(st[2][2], st[2][3]);
            unsigned pd0 = pack2bf(st[3][0], st[3][1]);
            unsigned pd1 = pack2bf(st[3][2], st[3][3]);
            sum += __shfl_xor(sum, 16);
            sum += __shfl_xor(sum, 32);
            const float inv = __builtin_amdgcn_rcpf(sum);
            asm("v_permlane32_swap_b32 %0, %1" : "+v"(pa0), "+v"(pb0));
            asm("v_permlane32_swap_b32 %0, %1" : "+v"(pa1), "+v"(pb1));
            asm("v_permlane32_swap_b32 %0, %1" : "+v"(pc0), "+v"(pd0));
            asm("v_permlane32_swap_b32 %0, %1" : "+v"(pc1), "+v"(pd1));
            unsigned sb0 = __builtin_amdgcn_ds_swizzle(pb0, 0x401F);
            unsigned sb1 = __builtin_amdgcn_ds_swizzle(pb1, 0x401F);
            unsigned sa0 = __builtin_amdgcn_ds_swizzle(pa0, 0x401F);
            unsigned sa1 = __builtin_amdgcn_ds_swizzle(pa1, 0x401F);
            unsigned sd0 = __builtin_amdgcn_ds_swizzle(pd0, 0x401F);
            unsigned sd1 = __builtin_amdgcn_ds_swizzle(pd1, 0x401F);
            unsigned sc0 = __builtin_amdgcn_ds_swizzle(pc0, 0x401F);
            unsigned sc1 = __builtin_amdgcn_ds_swizzle(pc1, 0x401F);
            u32x4 ptw0, ptw1;
            ptw0[0] = hi16 ? sb0 : pa0;
            ptw0[1] = hi16 ? sb1 : pa1;
            ptw0[2] = hi16 ? pb0 : sa0;
            ptw0[3] = hi16 ? pb1 : sa1;
            ptw1[0] = hi16 ? sd0 : pc0;
            ptw1[1] = hi16 ? sd1 : pc1;
            ptw1[2] = hi16 ? pd0 : sc0;
            ptw1[3] = hi16 ? pd1 : sc1;
            bf16x8 bp0 = __builtin_bit_cast(bf16x8, ptw0);
            bf16x8 bp1 = __builtin_bit_cast(bf16x8, ptw1);
            f32x4 ot[2];
            __builtin_amdgcn_s_setprio(1);
            #pragma unroll
            for (int dt = 0; dt < 2; ++dt) {
                const bf16* vrow = &VTs[(h * 32 + 16 * dt + lr) * VSTR + lq * 8];
                bf16x8 av0 = *(const bf16x8*)(vrow);
                bf16x8 av1 = *(const bf16x8*)(vrow + 32);
                ot[dt] = MFMA(av0, bp0, (f32x4{0.f, 0.f, 0.f, 0.f}));
                ot[dt] = MFMA(av1, bp1, ot[dt]);
            }
            __builtin_amdgcn_s_setprio(0);
            #pragma unroll
            for (int dt = 0; dt < 2; ++dt) {
                bf16x4 o4;
                #pragma unroll
                for (int r = 0; r < 4; ++r) o4[r] = (bf16)(ot[dt][r] * inv);
                *(bf16x4*)&BufB[(16 * m + lr) * XSTR + h * 32 + 16 * dt + 4 * lq] = o4;
            }
        }
    }
    __syncthreads();

    // ---- phase 3: proj + bias, swapped, dual-acc, pipelined weight loads ----
    {
        bf16x8 ofrag[2][6];
        #pragma unroll
        for (int mm = 0; mm < 2; ++mm)
            #pragma unroll
            for (int k = 0; k < 6; ++k)
                ofrag[mm][k] = *(const bf16x8*)&BufB[(32 * h0 + 16 * mm + lr) * XSTR + k * 32 + lq * 8];
        float* orow[2];
        bool   valid[2];
        #pragma unroll
        for (int mm = 0; mm < 2; ++mm) {
            const int row = 32 * h0 + 16 * mm + lr;
            valid[mm] = row < NTOK;
            int rr = valid[mm] ? row : 0;
            int ty = rr / 7, tx = rr % 7;
            int oy = wy * 7 + ty + SHIFTV; if (oy >= IMG) oy -= IMG;
            int ox = wx * 7 + tx + SHIFTV; if (ox >= IMG) ox -= IMG;
            orow[mm] = out + (((size_t)bimg * IMG + oy) * IMG + ox) * CDIM;
        }

        const bf16* pbase = wprojT + (size_t)lr * CDIM + lq * 8;
#define PPTR(nt) (pbase + (size_t)(nt) * (16 * CDIM))
#define COMP3(buf, nt) do { \
    f32x4 a0 = {0.f,0.f,0.f,0.f}, a1 = {0.f,0.f,0.f,0.f}; \
    _Pragma("unroll") for (int k = 0; k < 6; ++k) { \
        a0 = MFMA(buf[k], ofrag[0][k], a0); \
        a1 = MFMA(buf[k], ofrag[1][k], a1); } \
    const int c0_ = (nt) * 16 + 4 * lq; \
    const f32x4 bp_ = *(const f32x4*)&b_proj[c0_]; \
    if (valid[0]) { f32x4 v_; _Pragma("unroll") for (int r = 0; r < 4; ++r) v_[r] = a0[r] + bp_[r]; *(f32x4*)&orow[0][c0_] = v_; } \
    if (valid[1]) { f32x4 v_; _Pragma("unroll") for (int r = 0; r < 4; ++r) v_[r] = a1[r] + bp_[r]; *(f32x4*)&orow[1][c0_] = v_; } \
} while (0)

        bf16x8 pA[6], pB[6];
        LOADW6(pA, PPTR(cg));
        LOADW6(pB, PPTR(cg + 4)); COMP3(pA, cg);
        LOADW6(pA, PPTR(cg + 8)); COMP3(pB, cg + 4);
                                  COMP3(pA, cg + 8);
    }
}

extern "C" void kernel_launch(void* const* d_in, const int* in_sizes, int n_in,
                              void* d_out, int out_size, void* d_ws, size_t ws_size,
                              hipStream_t stream) {
    const float* x           = (const float*)d_in[0];
    const float* gamma       = (const float*)d_in[1];
    const float* beta        = (const float*)d_in[2];
    const float* w_qkv       = (const float*)d_in[3];
    const float* b_qkv       = (const float*)d_in[4];
    const float* rel_table   = (const float*)d_in[5];
    const float* w_proj      = (const float*)d_in[6];
    const float* b_proj      = (const float*)d_in[7];
    // d_in[8] = mask_matrix: recomputed inline from window coords
    float* out = (float*)d_out;

    bf16* wqkvT  = (bf16*)d_ws;
    bf16* wprojT = (bf16*)((char*)d_ws + (size_t)576 * 192 * 2);

    prep_weights<<<432, 256, 0, stream>>>(w_qkv, w_proj, wqkvT, wprojT);
    swin_block<<<4096, 512, 0, stream>>>(x, gamma, beta, wqkvT, b_qkv, rel_table,
                                         wprojT, b_proj, out);
}

// Round 23
// 324.827 us; speedup vs baseline: 1.0202x; 1.0202x over previous
//
#include <hip/hip_runtime.h>
#include <hip/hip_bf16.h>
#include <math.h>

typedef __bf16 bf16;
typedef __bf16 bf16x4 __attribute__((ext_vector_type(4)));
typedef __bf16 bf16x8 __attribute__((ext_vector_type(8)));
typedef float f32x4 __attribute__((ext_vector_type(4)));
typedef unsigned int u32x4 __attribute__((ext_vector_type(4)));

#define NHEADS 6
#define CDIM 192
#define IMG 56
#define NTOK 49
#define SHIFTV 3
#define XSTR 200   // padded row stride (bf16) for BufA/BufB: 400 B
#define VSTR 72    // padded stride for VT: 144 B
#define LOG2E 1.4426950408889634f
#define SCALE 0.17677669529663687f
#define MSKNEG (-100.0f * LOG2E)

#define MFMA(a, b, c) __builtin_amdgcn_mfma_f32_16x16x32_bf16(a, b, c, 0, 0, 0)

static __device__ __forceinline__ unsigned pack2bf(float lo, float hi) {
    unsigned short a = __builtin_bit_cast(unsigned short, (bf16)lo);
    unsigned short b = __builtin_bit_cast(unsigned short, (bf16)hi);
    return (unsigned)a | ((unsigned)b << 16);
}

// ---- weight prep: fp32 -> bf16, transposed to [N][K] ----
__global__ void prep_weights(const float* __restrict__ w_qkv, const float* __restrict__ w_proj,
                             bf16* __restrict__ wqkvT, bf16* __restrict__ wprojT) {
    int i = blockIdx.x * 256 + threadIdx.x;
    if (i < 576 * 192) {
        int n = i / 192, k = i % 192;
        wqkvT[i] = (bf16)w_qkv[k * 576 + n];
    }
    if (i < 192 * 192) {
        int n = i / 192, k = i % 192;
        wprojT[i] = (bf16)w_proj[k * 192 + n];
    }
}

__global__ __launch_bounds__(512, 4) void swin_block(
    const float* __restrict__ x, const float* __restrict__ gamma, const float* __restrict__ beta,
    const bf16* __restrict__ wqkvT, const float* __restrict__ b_qkv,
    const float* __restrict__ rel_table, const bf16* __restrict__ wprojT,
    const float* __restrict__ b_proj, float* __restrict__ out)
{
    __shared__ __align__(16) bf16 BufA[64 * XSTR];     // X (ph0-1), then K (in place)
    __shared__ __align__(16) bf16 BufB[64 * XSTR];     // Q (ph1-2), then O in place (ph2-3)
    __shared__ __align__(16) bf16 VTs[CDIM * VSTR];    // V transposed: [channel][token]
    __shared__ bf16 biasS[169 * NHEADS];               // rel-pos bias * log2e
    // total 80876 B -> 2 blocks/CU

    const int blk  = blockIdx.x;
    const int bimg = blk >> 6;
    const int wy   = (blk >> 3) & 7;
    const int wx   = blk & 7;
    const int tid  = threadIdx.x;
    const int wave = tid >> 6;   // 0..7
    const int lane = tid & 63;
    const int lr   = lane & 15;
    const int lq   = lane >> 4;
    const int h0   = wave & 1;
    const int cg   = wave >> 1;  // 0..3

    for (int i = tid; i < 169 * NHEADS; i += 512) biasS[i] = (bf16)(rel_table[i] * LOG2E);

    const bf16* wbase = wqkvT + (size_t)lr * CDIM + lq * 8;
#define WPTR(nt) (wbase + (size_t)(nt) * (16 * CDIM))
#define LOADW6(dst, p) do { const bf16* _p = (p); \
    _Pragma("unroll") for (int k = 0; k < 6; ++k) dst[k] = *(const bf16x8*)(_p + k * 32); } while (0)

    { // ---- phases 0-1 scope: bA/bB live only here ----
    bf16x8 bA[6], bB[6];

    // ---- phase 0: LN, 16 lanes per row (4 rows/wave/iter, 12 ch/lane); hoisted gamma/beta ----
    {
        const int c0 = lr * 12;
        const f32x4 gm0 = *(const f32x4*)&gamma[c0], gm1 = *(const f32x4*)&gamma[c0 + 4], gm2 = *(const f32x4*)&gamma[c0 + 8];
        const f32x4 bt0 = *(const f32x4*)&beta[c0],  bt1 = *(const f32x4*)&beta[c0 + 4],  bt2 = *(const f32x4*)&beta[c0 + 8];
        #pragma unroll
        for (int it = 0; it < 2; ++it) {
            const int t = it * 32 + wave * 4 + lq;   // 0..63, each (it,wave,lq) one row
            if (t < NTOK) {
                int ty = t / 7, tx = t % 7;
                int oy = wy * 7 + ty + SHIFTV; if (oy >= IMG) oy -= IMG;
                int ox = wx * 7 + tx + SHIFTV; if (ox >= IMG) ox -= IMG;
                const float* xp = x + (((size_t)bimg * IMG + oy) * IMG + ox) * CDIM + c0;
                f32x4 v0 = *(const f32x4*)(xp), v1 = *(const f32x4*)(xp + 4), v2 = *(const f32x4*)(xp + 8);
                float s = 0.f, ss = 0.f;
                #pragma unroll
                for (int r = 0; r < 4; ++r) {
                    s  += v0[r] + v1[r] + v2[r];
                    ss += v0[r] * v0[r] + v1[r] * v1[r] + v2[r] * v2[r];
                }
                #pragma unroll
                for (int off = 1; off < 16; off <<= 1) { s += __shfl_xor(s, off); ss += __shfl_xor(ss, off); }
                float mu  = s * (1.f / 192.f);
                float var = ss * (1.f / 192.f) - mu * mu;
                float rs  = rsqrtf(var + 1e-5f);
                bf16x4 o0, o1, o2;
                #pragma unroll
                for (int r = 0; r < 4; ++r) {
                    o0[r] = (bf16)((v0[r] - mu) * rs * gm0[r] + bt0[r]);
                    o1[r] = (bf16)((v1[r] - mu) * rs * gm1[r] + bt1[r]);
                    o2[r] = (bf16)((v2[r] - mu) * rs * gm2[r] + bt2[r]);
                }
                *(bf16x4*)&BufA[t * XSTR + c0    ] = o0;
                *(bf16x4*)&BufA[t * XSTR + c0 + 4] = o1;
                *(bf16x4*)&BufA[t * XSTR + c0 + 8] = o2;
            } else {
                bf16x4 z = {(bf16)0.f, (bf16)0.f, (bf16)0.f, (bf16)0.f};
                *(bf16x4*)&BufA[t * XSTR + c0    ] = z;
                *(bf16x4*)&BufA[t * XSTR + c0 + 4] = z;
                *(bf16x4*)&BufA[t * XSTR + c0 + 8] = z;
            }
        }
    }
    // prefetch first phase-1 weight hexad: ~300cy L2 latency hides under barrier + afrag ds_reads
    LOADW6(bA, WPTR(cg));
    __syncthreads();

    // ---- phase 1: QKV, software-pipelined weight loads (dual register buffers) ----
    {
        bf16x8 afrag[2][6];
        #pragma unroll
        for (int mm = 0; mm < 2; ++mm)
            #pragma unroll
            for (int k = 0; k < 6; ++k)
                afrag[mm][k] = *(const bf16x8*)&BufA[(32 * h0 + 16 * mm + lr) * XSTR + k * 32 + lq * 8];
        __syncthreads();   // all waves cached X before K overwrites BufA

        // Q/K (swapped): D token = 32h0+16mm+lr, channel packed (nt%12)*16+4lq+r
#define COMP_QK(buf, nt, dstb) do { \
    f32x4 a0 = {0.f,0.f,0.f,0.f}, a1 = {0.f,0.f,0.f,0.f}; \
    _Pragma("unroll") for (int k = 0; k < 6; ++k) { \
        a0 = MFMA(buf[k], afrag[0][k], a0); \
        a1 = MFMA(buf[k], afrag[1][k], a1); } \
    const int ccl_ = ((nt) % 12) * 16 + 4 * lq; \
    const f32x4 bq_ = *(const f32x4*)&b_qkv[(nt) * 16 + 4 * lq]; \
    bf16x4 v0_, v1_; \
    _Pragma("unroll") for (int r = 0; r < 4; ++r) { v0_[r] = (bf16)(a0[r] + bq_[r]); v1_[r] = (bf16)(a1[r] + bq_[r]); } \
    *(bf16x4*)&dstb[(32 * h0 + lr) * XSTR + ccl_] = v0_; \
    *(bf16x4*)&dstb[(32 * h0 + 16 + lr) * XSTR + ccl_] = v1_; } while (0)
        // V (unswapped): D channel = (nt-24)*16+lr, token packed 32h0+16mm+4lq+r
#define COMP_V(buf, nt) do { \
    f32x4 a0 = {0.f,0.f,0.f,0.f}, a1 = {0.f,0.f,0.f,0.f}; \
    _Pragma("unroll") for (int k = 0; k < 6; ++k) { \
        a0 = MFMA(afrag[0][k], buf[k], a0); \
        a1 = MFMA(afrag[1][k], buf[k], a1); } \
    const int cc_ = ((nt) - 24) * 16 + lr; \
    const float bb_ = b_qkv[384 + cc_]; \
    bf16x4 v0_, v1_; \
    _Pragma("unroll") for (int r = 0; r < 4; ++r) { v0_[r] = (bf16)(a0[r] + bb_); v1_[r] = (bf16)(a1[r] + bb_); } \
    *(bf16x4*)&VTs[cc_ * VSTR + 32 * h0 + 4 * lq] = v0_; \
    *(bf16x4*)&VTs[cc_ * VSTR + 32 * h0 + 16 + 4 * lq] = v1_; } while (0)

        LOADW6(bB, WPTR(cg + 4));  COMP_QK(bA, cg,      BufB);
        LOADW6(bA, WPTR(cg + 8));  COMP_QK(bB, cg + 4,  BufB);
        LOADW6(bB, WPTR(cg + 12)); COMP_QK(bA, cg + 8,  BufB);
        LOADW6(bA, WPTR(cg + 16)); COMP_QK(bB, cg + 12, BufA);
        LOADW6(bB, WPTR(cg + 20)); COMP_QK(bA, cg + 16, BufA);
        LOADW6(bA, WPTR(cg + 24)); COMP_QK(bB, cg + 20, BufA);
        LOADW6(bB, WPTR(cg + 28)); COMP_V (bA, cg + 24);
        LOADW6(bA, WPTR(cg + 32)); COMP_V (bB, cg + 28);
                                   COMP_V (bA, cg + 32);
    }
    } // ---- end phases 0-1 scope (bA/bB die) ----
    __syncthreads();

    // ---- phase 2: attention, swapped QK^T (S^T), LDS bias, NO-MAX softmax,
    //      DEFERRED normalization, permlane/swizzle P^T, setprio, Q-prefetch ----
    {
        const int m  = wave & 3;
        const int hg = wave >> 2;
        const int i  = 16 * m + lr;
        const int ic = i < NTOK ? i : NTOK - 1;
        const int iy = ic / 7, ix = ic % 7;
        const int ay = wy * 7 + iy, ax = wx * 7 + ix;
        const int ryi = (ay < 49) ? 0 : ((ay < 53) ? 1 : 2);
        const int rxi = (ax < 49) ? 0 : ((ax < 53) ? 1 : 2);
        int   rp[4][4];
        float msk[4][4];
        #pragma unroll
        for (int n = 0; n < 4; ++n)
            #pragma unroll
            for (int r = 0; r < 4; ++r) {
                int j = 16 * n + 4 * lq + r;
                if (j < NTOK) {
                    int jy = j / 7, jx = j % 7;
                    rp[n][r] = ((iy - jy + 6) * 13 + (ix - jx + 6)) * NHEADS;
                    int by = wy * 7 + jy, bx = wx * 7 + jx;
                    int ryj = (by < 49) ? 0 : ((by < 53) ? 1 : 2);
                    int rxj = (bx < 49) ? 0 : ((bx < 53) ? 1 : 2);
                    msk[n][r] = (ryi == ryj && rxi == rxj) ? 0.f : MSKNEG;
                } else { rp[n][r] = 0; msk[n][r] = -1e30f; }
            }
        const bool hi16 = (lane & 16) != 0;
        const float SC = SCALE * LOG2E;

        bf16x8 bq = *(const bf16x8*)&BufB[(16 * m + lr) * XSTR + (hg * 3) * 32 + lq * 8];

        #pragma unroll
        for (int hh = 0; hh < 3; ++hh) {
            const int h = hg * 3 + hh;
            f32x4 st[4];
            __builtin_amdgcn_s_setprio(1);
            #pragma unroll
            for (int n = 0; n < 4; ++n) {
                bf16x8 ak = *(const bf16x8*)&BufA[(16 * n + lr) * XSTR + h * 32 + lq * 8];
                st[n] = MFMA(ak, bq, (f32x4{0.f, 0.f, 0.f, 0.f}));
            }
            __builtin_amdgcn_s_setprio(0);
            float sum = 0.f;
            #pragma unroll
            for (int n = 0; n < 4; ++n)
                #pragma unroll
                for (int r = 0; r < 4; ++r) {
                    float e = exp2f(fmaf(st[n][r], SC, msk[n][r]) + (float)biasS[rp[n][r] + h]);
                    st[n][r] = e; sum += e;
                }
            if (hh < 2)
                bq = *(const bf16x8*)&BufB[(16 * m + lr) * XSTR + (h + 1) * 32 + lq * 8];
            unsigned pa0 = pack2bf(st[0][0], st[0][1]);
            unsigned pa1 = pack2bf(st[0][2], st[0][3]);
            unsigned pb0 = pack2bf(st[1][0], st[1][1]);
            unsigned pb1 = pack2bf(st[1][2], st[1][3]);
            unsigned pc0 = pack2bf(st[2][0], st[2][1]);
            unsigned pc1 = pack2bf(st[2][2], st[2][3]);
            unsigned pd0 = pack2bf(st[3][0], st[3][1]);
            unsigned pd1 = pack2bf(st[3][2], st[3][3]);
            sum += __shfl_xor(sum, 16);
            sum += __shfl_xor(sum, 32);
            const float inv = __builtin_amdgcn_rcpf(sum);
            asm("v_permlane32_swap_b32 %0, %1" : "+v"(pa0), "+v"(pb0));
            asm("v_permlane32_swap_b32 %0, %1" : "+v"(pa1), "+v"(pb1));
            asm("v_permlane32_swap_b32 %0, %1" : "+v"(pc0), "+v"(pd0));
            asm("v_permlane32_swap_b32 %0, %1" : "+v"(pc1), "+v"(pd1));
            unsigned sb0 = __builtin_amdgcn_ds_swizzle(pb0, 0x401F);
            unsigned sb1 = __builtin_amdgcn_ds_swizzle(pb1, 0x401F);
            unsigned sa0 = __builtin_amdgcn_ds_swizzle(pa0, 0x401F);
            unsigned sa1 = __builtin_amdgcn_ds_swizzle(pa1, 0x401F);
            unsigned sd0 = __builtin_amdgcn_ds_swizzle(pd0, 0x401F);
            unsigned sd1 = __builtin_amdgcn_ds_swizzle(pd1, 0x401F);
            unsigned sc0 = __builtin_amdgcn_ds_swizzle(pc0, 0x401F);
            unsigned sc1 = __builtin_amdgcn_ds_swizzle(pc1, 0x401F);
            u32x4 ptw0, ptw1;
            ptw0[0] = hi16 ? sb0 : pa0;
            ptw0[1] = hi16 ? sb1 : pa1;
            ptw0[2] = hi16 ? pb0 : sa0;
            ptw0[3] = hi16 ? pb1 : sa1;
            ptw1[0] = hi16 ? sd0 : pc0;
            ptw1[1] = hi16 ? sd1 : pc1;
            ptw1[2] = hi16 ? pd0 : sc0;
            ptw1[3] = hi16 ? pd1 : sc1;
            bf16x8 bp0 = __builtin_bit_cast(bf16x8, ptw0);
            bf16x8 bp1 = __builtin_bit_cast(bf16x8, ptw1);
            f32x4 ot[2];
            __builtin_amdgcn_s_setprio(1);
            #pragma unroll
            for (int dt = 0; dt < 2; ++dt) {
                const bf16* vrow = &VTs[(h * 32 + 16 * dt + lr) * VSTR + lq * 8];
                bf16x8 av0 = *(const bf16x8*)(vrow);
                bf16x8 av1 = *(const bf16x8*)(vrow + 32);
                ot[dt] = MFMA(av0, bp0, (f32x4{0.f, 0.f, 0.f, 0.f}));
                ot[dt] = MFMA(av1, bp1, ot[dt]);
            }
            __builtin_amdgcn_s_setprio(0);
            #pragma unroll
            for (int dt = 0; dt < 2; ++dt) {
                bf16x4 o4;
                #pragma unroll
                for (int r = 0; r < 4; ++r) o4[r] = (bf16)(ot[dt][r] * inv);
                *(bf16x4*)&BufB[(16 * m + lr) * XSTR + h * 32 + 16 * dt + 4 * lq] = o4;
            }
        }
    }

    // ---- phase 3: proj + bias, swapped, dual-acc, pipelined weight loads;
    //      first hexad prefetched ACROSS the phase-2->3 barrier (lowest-liveness point) ----
    {
        const bf16* pbase = wprojT + (size_t)lr * CDIM + lq * 8;
#define PPTR(nt) (pbase + (size_t)(nt) * (16 * CDIM))
        bf16x8 pA[6], pB[6];
        LOADW6(pA, PPTR(cg));   // issue before barrier: latency hides under barrier + ofrag reads
        __syncthreads();

        bf16x8 ofrag[2][6];
        #pragma unroll
        for (int mm = 0; mm < 2; ++mm)
            #pragma unroll
            for (int k = 0; k < 6; ++k)
                ofrag[mm][k] = *(const bf16x8*)&BufB[(32 * h0 + 16 * mm + lr) * XSTR + k * 32 + lq * 8];
        float* orow[2];
        bool   valid[2];
        #pragma unroll
        for (int mm = 0; mm < 2; ++mm) {
            const int row = 32 * h0 + 16 * mm + lr;
            valid[mm] = row < NTOK;
            int rr = valid[mm] ? row : 0;
            int ty = rr / 7, tx = rr % 7;
            int oy = wy * 7 + ty + SHIFTV; if (oy >= IMG) oy -= IMG;
            int ox = wx * 7 + tx + SHIFTV; if (ox >= IMG) ox -= IMG;
            orow[mm] = out + (((size_t)bimg * IMG + oy) * IMG + ox) * CDIM;
        }

#define COMP3(buf, nt) do { \
    f32x4 a0 = {0.f,0.f,0.f,0.f}, a1 = {0.f,0.f,0.f,0.f}; \
    _Pragma("unroll") for (int k = 0; k < 6; ++k) { \
        a0 = MFMA(buf[k], ofrag[0][k], a0); \
        a1 = MFMA(buf[k], ofrag[1][k], a1); } \
    const int c0_ = (nt) * 16 + 4 * lq; \
    const f32x4 bp_ = *(const f32x4*)&b_proj[c0_]; \
    if (valid[0]) { f32x4 v_; _Pragma("unroll") for (int r = 0; r < 4; ++r) v_[r] = a0[r] + bp_[r]; *(f32x4*)&orow[0][c0_] = v_; } \
    if (valid[1]) { f32x4 v_; _Pragma("unroll") for (int r = 0; r < 4; ++r) v_[r] = a1[r] + bp_[r]; *(f32x4*)&orow[1][c0_] = v_; } \
} while (0)

        LOADW6(pB, PPTR(cg + 4)); COMP3(pA, cg);
        LOADW6(pA, PPTR(cg + 8)); COMP3(pB, cg + 4);
                                  COMP3(pA, cg + 8);
    }
}

extern "C" void kernel_launch(void* const* d_in, const int* in_sizes, int n_in,
                              void* d_out, int out_size, void* d_ws, size_t ws_size,
                              hipStream_t stream) {
    const float* x           = (const float*)d_in[0];
    const float* gamma       = (const float*)d_in[1];
    const float* beta        = (const float*)d_in[2];
    const float* w_qkv       = (const float*)d_in[3];
    const float* b_qkv       = (const float*)d_in[4];
    const float* rel_table   = (const float*)d_in[5];
    const float* w_proj      = (const float*)d_in[6];
    const float* b_proj      = (const float*)d_in[7];
    // d_in[8] = mask_matrix: recomputed inline from window coords
    float* out = (float*)d_out;

    bf16* wqkvT  = (bf16*)d_ws;
    bf16* wprojT = (bf16*)((char*)d_ws + (size_t)576 * 192 * 2);

    prep_weights<<<432, 256, 0, stream>>>(w_qkv, w_proj, wqkvT, wprojT);
    swin_block<<<4096, 512, 0, stream>>>(x, gamma, beta, wqkvT, b_qkv, rel_table,
                                         wprojT, b_proj, out);
}

// Round 24
// 317.235 us; speedup vs baseline: 1.0446x; 1.0239x over previous
//
#include <hip/hip_runtime.h>
#include <hip/hip_bf16.h>
#include <math.h>

typedef __bf16 bf16;
typedef __bf16 bf16x4 __attribute__((ext_vector_type(4)));
typedef __bf16 bf16x8 __attribute__((ext_vector_type(8)));
typedef float f32x4 __attribute__((ext_vector_type(4)));
typedef unsigned int u32x4 __attribute__((ext_vector_type(4)));

#define NHEADS 6
#define CDIM 192
#define IMG 56
#define NTOK 49
#define SHIFTV 3
#define XSTR 200   // padded row stride (bf16) for BufA/BufB: 400 B
#define VSTR 72    // padded stride for VT: 144 B
#define LOG2E 1.4426950408889634f
#define SCALE 0.17677669529663687f
#define MSKNEG (-100.0f * LOG2E)

#define MFMA(a, b, c) __builtin_amdgcn_mfma_f32_16x16x32_bf16(a, b, c, 0, 0, 0)

static __device__ __forceinline__ unsigned pack2bf(float lo, float hi) {
    unsigned short a = __builtin_bit_cast(unsigned short, (bf16)lo);
    unsigned short b = __builtin_bit_cast(unsigned short, (bf16)hi);
    return (unsigned)a | ((unsigned)b << 16);
}

// ---- weight prep: fp32 -> bf16, transposed to [N][K] ----
__global__ void prep_weights(const float* __restrict__ w_qkv, const float* __restrict__ w_proj,
                             bf16* __restrict__ wqkvT, bf16* __restrict__ wprojT) {
    int i = blockIdx.x * 256 + threadIdx.x;
    if (i < 576 * 192) {
        int n = i / 192, k = i % 192;
        wqkvT[i] = (bf16)w_qkv[k * 576 + n];
    }
    if (i < 192 * 192) {
        int n = i / 192, k = i % 192;
        wprojT[i] = (bf16)w_proj[k * 192 + n];
    }
}

__global__ __launch_bounds__(512, 4) void swin_block(
    const float* __restrict__ x, const float* __restrict__ gamma, const float* __restrict__ beta,
    const bf16* __restrict__ wqkvT, const float* __restrict__ b_qkv,
    const float* __restrict__ rel_table, const bf16* __restrict__ wprojT,
    const float* __restrict__ b_proj, float* __restrict__ out)
{
    __shared__ __align__(16) bf16 BufA[64 * XSTR];     // X (ph0-1), then K (in place; read-only in ph2)
    __shared__ __align__(16) bf16 BufB[64 * XSTR];     // Q (ph1-2), then O in place (ph2-3)
    __shared__ __align__(16) bf16 VTs[CDIM * VSTR];    // V transposed: [channel][token]
    __shared__ bf16 biasS[169 * NHEADS];               // rel-pos bias * log2e
    // total 80876 B -> 2 blocks/CU

    const int blk  = blockIdx.x;
    const int bimg = blk >> 6;
    const int wy   = (blk >> 3) & 7;
    const int wx   = blk & 7;
    const int tid  = threadIdx.x;
    const int wave = tid >> 6;   // 0..7
    const int lane = tid & 63;
    const int lr   = lane & 15;
    const int lq   = lane >> 4;
    const int h0   = wave & 1;
    const int cg   = wave >> 1;  // 0..3

    for (int i = tid; i < 169 * NHEADS; i += 512) biasS[i] = (bf16)(rel_table[i] * LOG2E);

    const bf16* wbase = wqkvT + (size_t)lr * CDIM + lq * 8;
#define WPTR(nt) (wbase + (size_t)(nt) * (16 * CDIM))
#define LOADW6(dst, p) do { const bf16* _p = (p); \
    _Pragma("unroll") for (int k = 0; k < 6; ++k) dst[k] = *(const bf16x8*)(_p + k * 32); } while (0)

    { // ---- phases 0-1 scope: bA/bB live only here ----
    bf16x8 bA[6], bB[6];

    // ---- phase 0: LN, 16 lanes per row (4 rows/wave/iter, 12 ch/lane); hoisted gamma/beta ----
    {
        const int c0 = lr * 12;
        const f32x4 gm0 = *(const f32x4*)&gamma[c0], gm1 = *(const f32x4*)&gamma[c0 + 4], gm2 = *(const f32x4*)&gamma[c0 + 8];
        const f32x4 bt0 = *(const f32x4*)&beta[c0],  bt1 = *(const f32x4*)&beta[c0 + 4],  bt2 = *(const f32x4*)&beta[c0 + 8];
        #pragma unroll
        for (int it = 0; it < 2; ++it) {
            const int t = it * 32 + wave * 4 + lq;   // 0..63, each (it,wave,lq) one row
            if (t < NTOK) {
                int ty = t / 7, tx = t % 7;
                int oy = wy * 7 + ty + SHIFTV; if (oy >= IMG) oy -= IMG;
                int ox = wx * 7 + tx + SHIFTV; if (ox >= IMG) ox -= IMG;
                const float* xp = x + (((size_t)bimg * IMG + oy) * IMG + ox) * CDIM + c0;
                f32x4 v0 = *(const f32x4*)(xp), v1 = *(const f32x4*)(xp + 4), v2 = *(const f32x4*)(xp + 8);
                float s = 0.f, ss = 0.f;
                #pragma unroll
                for (int r = 0; r < 4; ++r) {
                    s  += v0[r] + v1[r] + v2[r];
                    ss += v0[r] * v0[r] + v1[r] * v1[r] + v2[r] * v2[r];
                }
                #pragma unroll
                for (int off = 1; off < 16; off <<= 1) { s += __shfl_xor(s, off); ss += __shfl_xor(ss, off); }
                float mu  = s * (1.f / 192.f);
                float var = ss * (1.f / 192.f) - mu * mu;
                float rs  = rsqrtf(var + 1e-5f);
                bf16x4 o0, o1, o2;
                #pragma unroll
                for (int r = 0; r < 4; ++r) {
                    o0[r] = (bf16)((v0[r] - mu) * rs * gm0[r] + bt0[r]);
                    o1[r] = (bf16)((v1[r] - mu) * rs * gm1[r] + bt1[r]);
                    o2[r] = (bf16)((v2[r] - mu) * rs * gm2[r] + bt2[r]);
                }
                *(bf16x4*)&BufA[t * XSTR + c0    ] = o0;
                *(bf16x4*)&BufA[t * XSTR + c0 + 4] = o1;
                *(bf16x4*)&BufA[t * XSTR + c0 + 8] = o2;
            } else {
                bf16x4 z = {(bf16)0.f, (bf16)0.f, (bf16)0.f, (bf16)0.f};
                *(bf16x4*)&BufA[t * XSTR + c0    ] = z;
                *(bf16x4*)&BufA[t * XSTR + c0 + 4] = z;
                *(bf16x4*)&BufA[t * XSTR + c0 + 8] = z;
            }
        }
    }
    // prefetch first phase-1 weight hexad: ~300cy L2 latency hides under barrier + afrag ds_reads
    LOADW6(bA, WPTR(cg));
    __syncthreads();

    // ---- phase 1: QKV, software-pipelined weight loads (dual register buffers) ----
    {
        bf16x8 afrag[2][6];
        #pragma unroll
        for (int mm = 0; mm < 2; ++mm)
            #pragma unroll
            for (int k = 0; k < 6; ++k)
                afrag[mm][k] = *(const bf16x8*)&BufA[(32 * h0 + 16 * mm + lr) * XSTR + k * 32 + lq * 8];
        __syncthreads();   // all waves cached X before K overwrites BufA

        // Q/K (swapped): D token = 32h0+16mm+lr, channel packed (nt%12)*16+4lq+r
#define COMP_QK(buf, nt, dstb) do { \
    f32x4 a0 = {0.f,0.f,0.f,0.f}, a1 = {0.f,0.f,0.f,0.f}; \
    _Pragma("unroll") for (int k = 0; k < 6; ++k) { \
        a0 = MFMA(buf[k], afrag[0][k], a0); \
        a1 = MFMA(buf[k], afrag[1][k], a1); } \
    const int ccl_ = ((nt) % 12) * 16 + 4 * lq; \
    const f32x4 bq_ = *(const f32x4*)&b_qkv[(nt) * 16 + 4 * lq]; \
    bf16x4 v0_, v1_; \
    _Pragma("unroll") for (int r = 0; r < 4; ++r) { v0_[r] = (bf16)(a0[r] + bq_[r]); v1_[r] = (bf16)(a1[r] + bq_[r]); } \
    *(bf16x4*)&dstb[(32 * h0 + lr) * XSTR + ccl_] = v0_; \
    *(bf16x4*)&dstb[(32 * h0 + 16 + lr) * XSTR + ccl_] = v1_; } while (0)
        // V (unswapped): D channel = (nt-24)*16+lr, token packed 32h0+16mm+4lq+r
#define COMP_V(buf, nt) do { \
    f32x4 a0 = {0.f,0.f,0.f,0.f}, a1 = {0.f,0.f,0.f,0.f}; \
    _Pragma("unroll") for (int k = 0; k < 6; ++k) { \
        a0 = MFMA(afrag[0][k], buf[k], a0); \
        a1 = MFMA(afrag[1][k], buf[k], a1); } \
    const int cc_ = ((nt) - 24) * 16 + lr; \
    const float bb_ = b_qkv[384 + cc_]; \
    bf16x4 v0_, v1_; \
    _Pragma("unroll") for (int r = 0; r < 4; ++r) { v0_[r] = (bf16)(a0[r] + bb_); v1_[r] = (bf16)(a1[r] + bb_); } \
    *(bf16x4*)&VTs[cc_ * VSTR + 32 * h0 + 4 * lq] = v0_; \
    *(bf16x4*)&VTs[cc_ * VSTR + 32 * h0 + 16 + 4 * lq] = v1_; } while (0)

        LOADW6(bB, WPTR(cg + 4));  COMP_QK(bA, cg,      BufB);
        LOADW6(bA, WPTR(cg + 8));  COMP_QK(bB, cg + 4,  BufB);
        LOADW6(bB, WPTR(cg + 12)); COMP_QK(bA, cg + 8,  BufB);
        LOADW6(bA, WPTR(cg + 16)); COMP_QK(bB, cg + 12, BufA);
        LOADW6(bB, WPTR(cg + 20)); COMP_QK(bA, cg + 16, BufA);
        LOADW6(bA, WPTR(cg + 24)); COMP_QK(bB, cg + 20, BufA);
        LOADW6(bB, WPTR(cg + 28)); COMP_V (bA, cg + 24);
        LOADW6(bA, WPTR(cg + 32)); COMP_V (bB, cg + 28);
                                   COMP_V (bA, cg + 32);
    }
    } // ---- end phases 0-1 scope (bA/bB die) ----
    __syncthreads();

    // ---- phase 2: attention; K-fragment (BufA, read-only in ph2) prefetched across heads ----
    {
        const int m  = wave & 3;
        const int hg = wave >> 2;
        const int i  = 16 * m + lr;
        const int ic = i < NTOK ? i : NTOK - 1;
        const int iy = ic / 7, ix = ic % 7;
        const int ay = wy * 7 + iy, ax = wx * 7 + ix;
        const int ryi = (ay < 49) ? 0 : ((ay < 53) ? 1 : 2);
        const int rxi = (ax < 49) ? 0 : ((ax < 53) ? 1 : 2);
        int   rp[4][4];
        float msk[4][4];
        #pragma unroll
        for (int n = 0; n < 4; ++n)
            #pragma unroll
            for (int r = 0; r < 4; ++r) {
                int j = 16 * n + 4 * lq + r;
                if (j < NTOK) {
                    int jy = j / 7, jx = j % 7;
                    rp[n][r] = ((iy - jy + 6) * 13 + (ix - jx + 6)) * NHEADS;
                    int by = wy * 7 + jy, bx = wx * 7 + jx;
                    int ryj = (by < 49) ? 0 : ((by < 53) ? 1 : 2);
                    int rxj = (bx < 49) ? 0 : ((bx < 53) ? 1 : 2);
                    msk[n][r] = (ryi == ryj && rxi == rxj) ? 0.f : MSKNEG;
                } else { rp[n][r] = 0; msk[n][r] = -1e30f; }
            }
        const bool hi16 = (lane & 16) != 0;
        const float SC = SCALE * LOG2E;
        const bf16* karow = &BufA[lr * XSTR + lq * 8];   // +16n*XSTR per fragment, +h*32 per head

        // pipelines: Q fragment (r18) and first two K fragments of head 0
        bf16x8 bq  = *(const bf16x8*)&BufB[(16 * m + lr) * XSTR + (hg * 3) * 32 + lq * 8];
        bf16x8 ak0 = *(const bf16x8*)(karow + (hg * 3) * 32);
        bf16x8 ak1 = *(const bf16x8*)(karow + 16 * XSTR + (hg * 3) * 32);

        #pragma unroll
        for (int hh = 0; hh < 3; ++hh) {
            const int h = hg * 3 + hh;
            f32x4 st[4];
            __builtin_amdgcn_s_setprio(1);
            st[0] = MFMA(ak0, bq, (f32x4{0.f, 0.f, 0.f, 0.f}));
            st[1] = MFMA(ak1, bq, (f32x4{0.f, 0.f, 0.f, 0.f}));
            {
                bf16x8 ak2 = *(const bf16x8*)(karow + 32 * XSTR + h * 32);
                bf16x8 ak3 = *(const bf16x8*)(karow + 48 * XSTR + h * 32);
                st[2] = MFMA(ak2, bq, (f32x4{0.f, 0.f, 0.f, 0.f}));
                st[3] = MFMA(ak3, bq, (f32x4{0.f, 0.f, 0.f, 0.f}));
            }
            __builtin_amdgcn_s_setprio(0);
            float sum = 0.f;
            #pragma unroll
            for (int n = 0; n < 4; ++n)
                #pragma unroll
                for (int r = 0; r < 4; ++r) {
                    float e = exp2f(fmaf(st[n][r], SC, msk[n][r]) + (float)biasS[rp[n][r] + h]);
                    st[n][r] = e; sum += e;
                }
            // prefetch next head's Q + first two K fragments (BufA untouched by ph2 stores)
            if (hh < 2) {
                bq  = *(const bf16x8*)&BufB[(16 * m + lr) * XSTR + (h + 1) * 32 + lq * 8];
                ak0 = *(const bf16x8*)(karow + (h + 1) * 32);
                ak1 = *(const bf16x8*)(karow + 16 * XSTR + (h + 1) * 32);
            }
            unsigned pa0 = pack2bf(st[0][0], st[0][1]);
            unsigned pa1 = pack2bf(st[0][2], st[0][3]);
            unsigned pb0 = pack2bf(st[1][0], st[1][1]);
            unsigned pb1 = pack2bf(st[1][2], st[1][3]);
            unsigned pc0 = pack2bf(st[2][0], st[2][1]);
            unsigned pc1 = pack2bf(st[2][2], st[2][3]);
            unsigned pd0 = pack2bf(st[3][0], st[3][1]);
            unsigned pd1 = pack2bf(st[3][2], st[3][3]);
            sum += __shfl_xor(sum, 16);
            sum += __shfl_xor(sum, 32);
            const float inv = __builtin_amdgcn_rcpf(sum);
            asm("v_permlane32_swap_b32 %0, %1" : "+v"(pa0), "+v"(pb0));
            asm("v_permlane32_swap_b32 %0, %1" : "+v"(pa1), "+v"(pb1));
            asm("v_permlane32_swap_b32 %0, %1" : "+v"(pc0), "+v"(pd0));
            asm("v_permlane32_swap_b32 %0, %1" : "+v"(pc1), "+v"(pd1));
            unsigned sb0 = __builtin_amdgcn_ds_swizzle(pb0, 0x401F);
            unsigned sb1 = __builtin_amdgcn_ds_swizzle(pb1, 0x401F);
            unsigned sa0 = __builtin_amdgcn_ds_swizzle(pa0, 0x401F);
            unsigned sa1 = __builtin_amdgcn_ds_swizzle(pa1, 0x401F);
            unsigned sd0 = __builtin_amdgcn_ds_swizzle(pd0, 0x401F);
            unsigned sd1 = __builtin_amdgcn_ds_swizzle(pd1, 0x401F);
            unsigned sc0 = __builtin_amdgcn_ds_swizzle(pc0, 0x401F);
            unsigned sc1 = __builtin_amdgcn_ds_swizzle(pc1, 0x401F);
            u32x4 ptw0, ptw1;
            ptw0[0] = hi16 ? sb0 : pa0;
            ptw0[1] = hi16 ? sb1 : pa1;
            ptw0[2] = hi16 ? pb0 : sa0;
            ptw0[3] = hi16 ? pb1 : sa1;
            ptw1[0] = hi16 ? sd0 : pc0;
            ptw1[1] = hi16 ? sd1 : pc1;
            ptw1[2] = hi16 ? pd0 : sc0;
            ptw1[3] = hi16 ? pd1 : sc1;
            bf16x8 bp0 = __builtin_bit_cast(bf16x8, ptw0);
            bf16x8 bp1 = __builtin_bit_cast(bf16x8, ptw1);
            f32x4 ot[2];
            __builtin_amdgcn_s_setprio(1);
            #pragma unroll
            for (int dt = 0; dt < 2; ++dt) {
                const bf16* vrow = &VTs[(h * 32 + 16 * dt + lr) * VSTR + lq * 8];
                bf16x8 av0 = *(const bf16x8*)(vrow);
                bf16x8 av1 = *(const bf16x8*)(vrow + 32);
                ot[dt] = MFMA(av0, bp0, (f32x4{0.f, 0.f, 0.f, 0.f}));
                ot[dt] = MFMA(av1, bp1, ot[dt]);
            }
            __builtin_amdgcn_s_setprio(0);
            #pragma unroll
            for (int dt = 0; dt < 2; ++dt) {
                bf16x4 o4;
                #pragma unroll
                for (int r = 0; r < 4; ++r) o4[r] = (bf16)(ot[dt][r] * inv);
                *(bf16x4*)&BufB[(16 * m + lr) * XSTR + h * 32 + 16 * dt + 4 * lq] = o4;
            }
        }
    }

    // ---- phase 3: proj + bias, swapped, dual-acc, pipelined weight loads;
    //      first hexad prefetched ACROSS the phase-2->3 barrier (lowest-liveness point) ----
    {
        const bf16* pbase = wprojT + (size_t)lr * CDIM + lq * 8;
#define PPTR(nt) (pbase + (size_t)(nt) * (16 * CDIM))
        bf16x8 pA[6], pB[6];
        LOADW6(pA, PPTR(cg));   // issue before barrier: latency hides under barrier + ofrag reads
        __syncthreads();

        bf16x8 ofrag[2][6];
        #pragma unroll
        for (int mm = 0; mm < 2; ++mm)
            #pragma unroll
            for (int k = 0; k < 6; ++k)
                ofrag[mm][k] = *(const bf16x8*)&BufB[(32 * h0 + 16 * mm + lr) * XSTR + k * 32 + lq * 8];
        float* orow[2];
        bool   valid[2];
        #pragma unroll
        for (int mm = 0; mm < 2; ++mm) {
            const int row = 32 * h0 + 16 * mm + lr;
            valid[mm] = row < NTOK;
            int rr = valid[mm] ? row : 0;
            int ty = rr / 7, tx = rr % 7;
            int oy = wy * 7 + ty + SHIFTV; if (oy >= IMG) oy -= IMG;
            int ox = wx * 7 + tx + SHIFTV; if (ox >= IMG) ox -= IMG;
            orow[mm] = out + (((size_t)bimg * IMG + oy) * IMG + ox) * CDIM;
        }

#define COMP3(buf, nt) do { \
    f32x4 a0 = {0.f,0.f,0.f,0.f}, a1 = {0.f,0.f,0.f,0.f}; \
    _Pragma("unroll") for (int k = 0; k < 6; ++k) { \
        a0 = MFMA(buf[k], ofrag[0][k], a0); \
        a1 = MFMA(buf[k], ofrag[1][k], a1); } \
    const int c0_ = (nt) * 16 + 4 * lq; \
    const f32x4 bp_ = *(const f32x4*)&b_proj[c0_]; \
    if (valid[0]) { f32x4 v_; _Pragma("unroll") for (int r = 0; r < 4; ++r) v_[r] = a0[r] + bp_[r]; *(f32x4*)&orow[0][c0_] = v_; } \
    if (valid[1]) { f32x4 v_; _Pragma("unroll") for (int r = 0; r < 4; ++r) v_[r] = a1[r] + bp_[r]; *(f32x4*)&orow[1][c0_] = v_; } \
} while (0)

        LOADW6(pB, PPTR(cg + 4)); COMP3(pA, cg);
        LOADW6(pA, PPTR(cg + 8)); COMP3(pB, cg + 4);
                                  COMP3(pA, cg + 8);
    }
}

extern "C" void kernel_launch(void* const* d_in, const int* in_sizes, int n_in,
                              void* d_out, int out_size, void* d_ws, size_t ws_size,
                              hipStream_t stream) {
    const float* x           = (const float*)d_in[0];
    const float* gamma       = (const float*)d_in[1];
    const float* beta        = (const float*)d_in[2];
    const float* w_qkv       = (const float*)d_in[3];
    const float* b_qkv       = (const float*)d_in[4];
    const float* rel_table   = (const float*)d_in[5];
    const float* w_proj      = (const float*)d_in[6];
    const float* b_proj      = (const float*)d_in[7];
    // d_in[8] = mask_matrix: recomputed inline from window coords
    float* out = (float*)d_out;

    bf16* wqkvT  = (bf16*)d_ws;
    bf16* wprojT = (bf16*)((char*)d_ws + (size_t)576 * 192 * 2);

    prep_weights<<<432, 256, 0, stream>>>(w_qkv, w_proj, wqkvT, wprojT);
    swin_block<<<4096, 512, 0, stream>>>(x, gamma, beta, wqkvT, b_qkv, rel_table,
                                         wprojT, b_proj, out);
}